// Round 2
// baseline (644.475 us; speedup 1.0000x reference)
//
#include <hip/hip_runtime.h>
#include <math.h>

// Problem constants (B,R,L,H)=(2,64,512,1024), NH=8, HD=64, AH=512
typedef __attribute__((ext_vector_type(8))) short short8;   // 8 bf16 (4 VGPR)
typedef __attribute__((ext_vector_type(4))) float floatx4;  // MFMA acc

__device__ __forceinline__ unsigned int pack2_trunc(float a, float b) {
  // two f32 -> packed bf16 (truncate) : 3 VALU
  return (__float_as_uint(a) >> 16) | (__float_as_uint(b) & 0xffff0000u);
}
__device__ __forceinline__ unsigned short f2bf_rne(float x) {
  unsigned int u = __float_as_uint(x);
  u += 0x7fff + ((u >> 16) & 1);
  return (unsigned short)(u >> 16);
}
__device__ __forceinline__ float bflo(unsigned int u) { return __uint_as_float(u << 16); }
__device__ __forceinline__ float bfhi(unsigned int u) { return __uint_as_float(u & 0xffff0000u); }

// ---------------------------------------------------------------------------
// Kernel 0: one-time Wv fp32 -> bf16 cast (trunc, matching staging bit-exact).
// ---------------------------------------------------------------------------
__global__ __launch_bounds__(256) void wcast_kernel(
    const float* __restrict__ W, unsigned short* __restrict__ Wb)
{
  size_t i = (size_t)blockIdx.x * 256 + threadIdx.x;
  const float4* p = (const float4*)(W + i * 8);
  float4 a0 = p[0], a1 = p[1];
  uint4 w;
  w.x = pack2_trunc(a0.x, a0.y); w.y = pack2_trunc(a0.z, a0.w);
  w.z = pack2_trunc(a1.x, a1.y); w.w = pack2_trunc(a1.z, a1.w);
  *(uint4*)&Wb[i * 8] = w;
}

// ---------------------------------------------------------------------------
// Kernel 1: Q/K projection.  C[m=(b,l)][n=ah] = row0 @ W^T + bias, bf16 out
// row-major (M=1024, N=512).  grid=(4, 8, 2) z: 0=Q 1=K.  128x128 tile, BK=64.
// ---------------------------------------------------------------------------
__global__ __launch_bounds__(256, 2) void qk_proj_kernel(
    const float* __restrict__ hid,
    const float* __restrict__ Wq, const float* __restrict__ bq,
    const float* __restrict__ Wk, const float* __restrict__ bk,
    unsigned short* __restrict__ Qr, unsigned short* __restrict__ Kr)
{
  const float* W = blockIdx.z ? Wk : Wq;
  const float* bias = blockIdx.z ? bk : bq;
  unsigned short* out = blockIdx.z ? Kr : Qr;

  __shared__ unsigned short As[128][72];
  __shared__ unsigned short Bs[128][72];
  const int tid = threadIdx.x;
  const int m0 = blockIdx.y * 128;      // m = b*512 + l
  const int n0 = blockIdx.x * 128;
  const int bidx = m0 >> 9;
  const int l0 = m0 & 511;
  const float* Abase = hid + ((size_t)bidx * 32768 + l0) * 1024;  // hidden[b,0,l,:]
  const float* Bbase = W + (size_t)n0 * 1024;

  const int srow = tid >> 1;
  const int shalf = (tid & 1) * 32;
  const int lane = tid & 63;
  const int wave = tid >> 6;
  const int wm = (wave >> 1) * 64, wn = (wave & 1) * 64;
  const int mr = lane & 15, kq = lane >> 4;

  floatx4 acc[4][4];
#pragma unroll
  for (int i = 0; i < 4; ++i)
#pragma unroll
    for (int j = 0; j < 4; ++j) acc[i][j] = (floatx4){0.f, 0.f, 0.f, 0.f};

  for (int k0 = 0; k0 < 1024; k0 += 64) {
    const float4* ap = (const float4*)(Abase + (size_t)srow * 1024 + k0 + shalf);
    const float4* bp = (const float4*)(Bbase + (size_t)srow * 1024 + k0 + shalf);
#pragma unroll
    for (int j = 0; j < 4; ++j) {
      float4 a0 = ap[2 * j], a1 = ap[2 * j + 1];
      float4 b0 = bp[2 * j], b1 = bp[2 * j + 1];
      uint4 wa, wb;
      wa.x = pack2_trunc(a0.x, a0.y); wa.y = pack2_trunc(a0.z, a0.w);
      wa.z = pack2_trunc(a1.x, a1.y); wa.w = pack2_trunc(a1.z, a1.w);
      wb.x = pack2_trunc(b0.x, b0.y); wb.y = pack2_trunc(b0.z, b0.w);
      wb.z = pack2_trunc(b1.x, b1.y); wb.w = pack2_trunc(b1.z, b1.w);
      *(uint4*)&As[srow][shalf + j * 8] = wa;
      *(uint4*)&Bs[srow][shalf + j * 8] = wb;
    }
    __syncthreads();
#pragma unroll
    for (int ks = 0; ks < 2; ++ks) {
      short8 af[4], bfr[4];
#pragma unroll
      for (int i = 0; i < 4; ++i)
        af[i] = *(const short8*)&As[wm + i * 16 + mr][ks * 32 + kq * 8];
#pragma unroll
      for (int i = 0; i < 4; ++i)
        bfr[i] = *(const short8*)&Bs[wn + i * 16 + mr][ks * 32 + kq * 8];
#pragma unroll
      for (int i = 0; i < 4; ++i)
#pragma unroll
        for (int j = 0; j < 4; ++j)
          acc[i][j] = __builtin_amdgcn_mfma_f32_16x16x32_bf16(af[i], bfr[j], acc[i][j], 0, 0, 0);
    }
    __syncthreads();
  }

#pragma unroll
  for (int j = 0; j < 4; ++j) {
    int gn = n0 + wn + j * 16 + mr;
    float bb = bias[gn];
#pragma unroll
    for (int i = 0; i < 4; ++i) {
      int gm = m0 + wm + i * 16 + kq * 4;
      floatx4 a = acc[i][j];
#pragma unroll
      for (int rg = 0; rg < 4; ++rg)
        out[(size_t)(gm + rg) * 512 + gn] = f2bf_rne(a[rg] + bb);
    }
  }
}

// ---------------------------------------------------------------------------
// Kernel 2 (MFMA rewrite): rope(Q) @ rope(K)^T / 8 -> softmax -> probs bf16.
// grid=(8 q-tiles of 64, 16 bn), block 256 (4 waves).  Per block: 64 q rows x
// full k=512.  K rope'd once into LDS [512][72] bf16 (144B row stride -> 16B
// aligned, 2-way-bank-free ds_read_b128).  Q rope'd in-register into MFMA A
// frags (pairs (2i,2i+1) are intra-fragment).  Wave tile 16q x 512k,
// acc[32]; softmax fully in-wave: row=(kq,rg), reduce over mr lanes via
// shfl_xor 1..8 (stays inside the 16-lane group).
// ---------------------------------------------------------------------------
__global__ __launch_bounds__(256, 2) void scores_softmax_kernel(
    const unsigned short* __restrict__ Qr,
    const unsigned short* __restrict__ Kr,
    const float* __restrict__ sinu,
    unsigned short* __restrict__ probs)
{
  __shared__ unsigned short Ks[512][72];
  const int tid = threadIdx.x;
  const int bn = blockIdx.y;
  const int b = bn >> 3, h = bn & 7;
  const int q0 = blockIdx.x * 64;
  const int lane = tid & 63, wave = tid >> 6;
  const int mr = lane & 15, kq = lane >> 4;

  // stage rope'd K into LDS (bit-matches old path: trunc pack)
  for (int it = tid; it < 4096; it += 256) {
    int k = it >> 3, c = it & 7;
    uint4 v = *(const uint4*)(Kr + ((size_t)b * 512 + k) * 512 + h * 64 + c * 8);
    unsigned int uu[4] = {v.x, v.y, v.z, v.w};
    unsigned int res[4];
#pragma unroll
    for (int p = 0; p < 4; ++p) {
      int i = c * 4 + p;  // pair index, d = 2i, 2i+1
      float x0 = bflo(uu[p]), x1 = bfhi(uu[p]);
      float sn = sinu[k * 64 + i], cs = sinu[k * 64 + 32 + i];
      res[p] = pack2_trunc(x0 * cs - x1 * sn, x1 * cs + x0 * sn);
    }
    uint4 w; w.x = res[0]; w.y = res[1]; w.z = res[2]; w.w = res[3];
    *(uint4*)&Ks[k][c * 8] = w;
  }

  // rope'd Q fragments in registers (1/sqrt(64) folded in)
  const int gq_load = q0 + wave * 16 + mr;
  short8 aq[2];
#pragma unroll
  for (int ks = 0; ks < 2; ++ks) {
    int d0 = ks * 32 + kq * 8;
    uint4 v = *(const uint4*)(Qr + ((size_t)b * 512 + gq_load) * 512 + h * 64 + d0);
    unsigned int uu[4] = {v.x, v.y, v.z, v.w};
    union { short8 s; unsigned short u[8]; } r;
#pragma unroll
    for (int p = 0; p < 4; ++p) {
      int i = (d0 >> 1) + p;
      float x0 = bflo(uu[p]), x1 = bfhi(uu[p]);
      float sn = sinu[gq_load * 64 + i], cs = sinu[gq_load * 64 + 32 + i];
      r.u[2 * p]     = f2bf_rne((x0 * cs - x1 * sn) * 0.125f);
      r.u[2 * p + 1] = f2bf_rne((x1 * cs + x0 * sn) * 0.125f);
    }
    aq[ks] = r.s;
  }
  __syncthreads();

  floatx4 acc[32];
#pragma unroll
  for (int j = 0; j < 32; ++j) acc[j] = (floatx4){0.f, 0.f, 0.f, 0.f};
#pragma unroll
  for (int j = 0; j < 32; ++j) {
    short8 b0 = *(const short8*)&Ks[j * 16 + mr][kq * 8];
    short8 b1 = *(const short8*)&Ks[j * 16 + mr][32 + kq * 8];
    acc[j] = __builtin_amdgcn_mfma_f32_16x16x32_bf16(aq[0], b0, acc[j], 0, 0, 0);
    acc[j] = __builtin_amdgcn_mfma_f32_16x16x32_bf16(aq[1], b1, acc[j], 0, 0, 0);
  }

  // in-wave softmax: lane holds S[q0+wave*16+kq*4+rg][j*16+mr]
  float mx[4] = {-1e30f, -1e30f, -1e30f, -1e30f};
#pragma unroll
  for (int j = 0; j < 32; ++j)
#pragma unroll
    for (int rg = 0; rg < 4; ++rg) mx[rg] = fmaxf(mx[rg], acc[j][rg]);
#pragma unroll
  for (int rg = 0; rg < 4; ++rg)
#pragma unroll
    for (int off = 1; off < 16; off <<= 1) mx[rg] = fmaxf(mx[rg], __shfl_xor(mx[rg], off));
  float sum[4] = {0.f, 0.f, 0.f, 0.f};
#pragma unroll
  for (int j = 0; j < 32; ++j)
#pragma unroll
    for (int rg = 0; rg < 4; ++rg) {
      float e = __expf(acc[j][rg] - mx[rg]);
      acc[j][rg] = e; sum[rg] += e;
    }
#pragma unroll
  for (int rg = 0; rg < 4; ++rg)
#pragma unroll
    for (int off = 1; off < 16; off <<= 1) sum[rg] += __shfl_xor(sum[rg], off);
#pragma unroll
  for (int rg = 0; rg < 4; ++rg) {
    float inv = 1.0f / sum[rg];
    unsigned short* prow = probs + ((size_t)bn * 512 + q0 + wave * 16 + kq * 4 + rg) * 512;
#pragma unroll
    for (int j = 0; j < 32; ++j) prow[j * 16 + mr] = f2bf_rne(acc[j][rg] * inv);
  }
}

// ---------------------------------------------------------------------------
// Kernel 3: V projection, full-N tile, A double-buffered, B-frags direct from
// L2-resident bf16 Wvb (no Bs LDS, no staging barrier for B).  512 thr =
// 8 waves (2m x 4n), wave 64x128, acc[4][8].  One barrier per k-step; next
// A-tile global loads issued before compute (latency hidden under MFMA).
// LDS 2x18.4 KB.  grid=(512).
// ---------------------------------------------------------------------------
__global__ __launch_bounds__(512, 2) void vproj_kernel(
    const float* __restrict__ hid, const unsigned short* __restrict__ Wvb,
    const float* __restrict__ bv, unsigned short* __restrict__ VT)
{
  __shared__ unsigned short As[2][128][72];
  const int tid = threadIdx.x;
  const int m0 = blockIdx.x * 128;
  const float* Abase = hid + (size_t)m0 * 1024;
  const int lane = tid & 63, wave = tid >> 6;
  const int wm = (wave >> 2) * 64, wn = (wave & 3) * 128;
  const int mr = lane & 15, kq = lane >> 4;
  const int arow = tid >> 2, aseg = tid & 3;

  floatx4 acc[4][8];
#pragma unroll
  for (int i = 0; i < 4; ++i)
#pragma unroll
    for (int j = 0; j < 8; ++j) acc[i][j] = (floatx4){0.f, 0.f, 0.f, 0.f};

  const unsigned short* Bl = Wvb + (size_t)(wn + mr) * 1024 + kq * 8;
  const float* aptr = Abase + (size_t)arow * 1024 + aseg * 16;

  {  // prologue: stage k0=0
    const float4* ap = (const float4*)aptr;
    float4 a0 = ap[0], a1 = ap[1], a2 = ap[2], a3 = ap[3];
    uint4 w0, w1;
    w0.x = pack2_trunc(a0.x, a0.y); w0.y = pack2_trunc(a0.z, a0.w);
    w0.z = pack2_trunc(a1.x, a1.y); w0.w = pack2_trunc(a1.z, a1.w);
    w1.x = pack2_trunc(a2.x, a2.y); w1.y = pack2_trunc(a2.z, a2.w);
    w1.z = pack2_trunc(a3.x, a3.y); w1.w = pack2_trunc(a3.z, a3.w);
    *(uint4*)&As[0][arow][aseg * 16] = w0;
    *(uint4*)&As[0][arow][aseg * 16 + 8] = w1;
  }
  int cur = 0;
  for (int t = 0; t < 16; ++t) {
    const int k0 = t * 64;
    __syncthreads();
    float4 a0, a1, a2, a3;
    if (t < 15) {  // issue next A-tile loads early (uniform branch)
      const float4* ap = (const float4*)(aptr + k0 + 64);
      a0 = ap[0]; a1 = ap[1]; a2 = ap[2]; a3 = ap[3];
    }
#pragma unroll
    for (int ks = 0; ks < 2; ++ks) {
      short8 af[4], bfr[8];
#pragma unroll
      for (int i = 0; i < 4; ++i)
        af[i] = *(const short8*)&As[cur][wm + i * 16 + mr][ks * 32 + kq * 8];
#pragma unroll
      for (int j = 0; j < 8; ++j)
        bfr[j] = *(const short8*)(Bl + (size_t)j * 16384 + k0 + ks * 32);
#pragma unroll
      for (int i = 0; i < 4; ++i)
#pragma unroll
        for (int j = 0; j < 8; ++j)
          acc[i][j] = __builtin_amdgcn_mfma_f32_16x16x32_bf16(af[i], bfr[j], acc[i][j], 0, 0, 0);
    }
    if (t < 15) {
      uint4 w0, w1;
      w0.x = pack2_trunc(a0.x, a0.y); w0.y = pack2_trunc(a0.z, a0.w);
      w0.z = pack2_trunc(a1.x, a1.y); w0.w = pack2_trunc(a1.z, a1.w);
      w1.x = pack2_trunc(a2.x, a2.y); w1.y = pack2_trunc(a2.z, a2.w);
      w1.z = pack2_trunc(a3.x, a3.y); w1.w = pack2_trunc(a3.z, a3.w);
      *(uint4*)&As[cur ^ 1][arow][aseg * 16] = w0;
      *(uint4*)&As[cur ^ 1][arow][aseg * 16 + 8] = w1;
      cur ^= 1;
    }
  }

  // m-tile (128 rows) sits inside one (b,r): 512 % 128 == 0
  const int bidx = m0 >> 15;
  const int rr = (m0 >> 9) & 63;
  const int l0 = m0 & 511;
#pragma unroll
  for (int j = 0; j < 8; ++j) {
    int gn = wn + j * 16 + mr;
    int hh = gn >> 6, dd = gn & 63;
    float bb = bv[gn];
    size_t colbase = ((size_t)(bidx * 8 + hh) * 4096 + rr * 64 + dd) * 512;
#pragma unroll
    for (int i = 0; i < 4; ++i) {
      int gl = l0 + wm + i * 16 + kq * 4;  // 4 consecutive l per lane
      floatx4 a = acc[i][j];
      uint2 pk;
      pk.x = (unsigned int)f2bf_rne(a[0] + bb) | ((unsigned int)f2bf_rne(a[1] + bb) << 16);
      pk.y = (unsigned int)f2bf_rne(a[2] + bb) | ((unsigned int)f2bf_rne(a[3] + bb) << 16);
      *(uint2*)&VT[colbase + gl] = pk;
    }
  }
}

// ---------------------------------------------------------------------------
// Kernel 4: ctx.  Per z=(b,n): C[q][r*64+d] = probs[b,n] (512x512) @
// V_T[b,n] (4096x512 B^T).  Epilogue transposes through LDS so stores are
// 256B-contiguous float4 runs (was 64B dword scatter).  grid=(32, 4, 16).
// ---------------------------------------------------------------------------
__global__ __launch_bounds__(256, 2) void ctx_kernel(
    const unsigned short* __restrict__ probs,
    const unsigned short* __restrict__ VT,
    float* __restrict__ out)
{
  __shared__ unsigned short As[128][72];
  __shared__ unsigned short Bs[128][72];
  __shared__ float Cf[32][132];
  const int tid = threadIdx.x;
  const int n0 = blockIdx.x * 128;
  const int m0 = blockIdx.y * 128;
  const int z = blockIdx.z;  // b*8+h
  const unsigned short* Ab = probs + (size_t)z * 512 * 512;
  const unsigned short* Bb = VT + (size_t)z * 4096 * 512;

  const int srow = tid >> 1;
  const int shalf = (tid & 1) * 32;
  const int lane = tid & 63;
  const int wave = tid >> 6;
  const int wm = (wave >> 1) * 64, wn = (wave & 1) * 64;
  const int mr = lane & 15, kq = lane >> 4;

  floatx4 acc[4][4];
#pragma unroll
  for (int i = 0; i < 4; ++i)
#pragma unroll
    for (int j = 0; j < 4; ++j) acc[i][j] = (floatx4){0.f, 0.f, 0.f, 0.f};

  for (int k0 = 0; k0 < 512; k0 += 64) {
    const uint4* ap = (const uint4*)(Ab + (size_t)(m0 + srow) * 512 + k0 + shalf);
    const uint4* bp = (const uint4*)(Bb + (size_t)(n0 + srow) * 512 + k0 + shalf);
#pragma unroll
    for (int j = 0; j < 4; ++j) {
      *(uint4*)&As[srow][shalf + j * 8] = ap[j];
      *(uint4*)&Bs[srow][shalf + j * 8] = bp[j];
    }
    __syncthreads();
#pragma unroll
    for (int ks = 0; ks < 2; ++ks) {
      short8 af[4], bfr[4];
#pragma unroll
      for (int i = 0; i < 4; ++i)
        af[i] = *(const short8*)&As[wm + i * 16 + mr][ks * 32 + kq * 8];
#pragma unroll
      for (int i = 0; i < 4; ++i)
        bfr[i] = *(const short8*)&Bs[wn + i * 16 + mr][ks * 32 + kq * 8];
#pragma unroll
      for (int i = 0; i < 4; ++i)
#pragma unroll
        for (int j = 0; j < 4; ++j)
          acc[i][j] = __builtin_amdgcn_mfma_f32_16x16x32_bf16(af[i], bfr[j], acc[i][j], 0, 0, 0);
    }
    __syncthreads();
  }

  // Epilogue: 4 passes of 32 rows x 128 cols through LDS -> 256B stores.
  const int bz = z >> 3, hh = z & 7;
  const int lrw = (wave >> 1) * 16 + kq * 4;       // writer local row (+rg)
  const int lr2 = tid >> 3, seg = tid & 7;         // reader: row, 16-float seg
  const int gqb = m0 + (lr2 >> 4) * 64 + (lr2 & 15);
  const int gn2 = n0 + seg * 16;
  const int rr2 = gn2 >> 6, dd2 = gn2 & 63;
  float* obase = out + (size_t)(bz * 64 + rr2) * 262144 + hh * 64 + dd2;
#pragma unroll
  for (int i = 0; i < 4; ++i) {
    __syncthreads();
#pragma unroll
    for (int j = 0; j < 4; ++j) {
      floatx4 a = acc[i][j];
      int col = wn + j * 16 + mr;
#pragma unroll
      for (int rg = 0; rg < 4; ++rg) Cf[lrw + rg][col] = a[rg];
    }
    __syncthreads();
    float* op = obase + (size_t)(gqb + i * 16) * 512;
#pragma unroll
    for (int e = 0; e < 4; ++e)
      *(float4*)&op[e * 4] = *(const float4*)&Cf[lr2][seg * 16 + e * 4];
  }
}

// ---------------------------------------------------------------------------
extern "C" void kernel_launch(void* const* d_in, const int* in_sizes, int n_in,
                              void* d_out, int out_size, void* d_ws, size_t ws_size,
                              hipStream_t stream) {
  const float* hid  = (const float*)d_in[0];
  const float* sinu = (const float*)d_in[1];
  const float* Wq = (const float*)d_in[2];
  const float* bq = (const float*)d_in[3];
  const float* Wk = (const float*)d_in[4];
  const float* bk = (const float*)d_in[5];
  const float* Wv = (const float*)d_in[6];
  const float* bv = (const float*)d_in[7];
  float* out = (float*)d_out;

  // workspace layout (needs 80 MB):
  //  [0,1MB)   Qr  bf16 [b][l][ah]
  //  [1,2MB)   Kr  bf16 [b][l][ah]
  //  [2,10MB)  probs bf16 [b][n][q][k]
  //  [10,11MB) Wvb bf16 [ah][h]  (pre-cast Wv)
  //  [16,80MB) V_T bf16 [b][n][r*64+d][l]
  char* ws = (char*)d_ws;
  unsigned short* Qr = (unsigned short*)(ws);
  unsigned short* Kr = (unsigned short*)(ws + (1u << 20));
  unsigned short* probs = (unsigned short*)(ws + (2u << 20));
  unsigned short* Wvb = (unsigned short*)(ws + (10u << 20));
  unsigned short* VT = (unsigned short*)(ws + (16u << 20));

  wcast_kernel<<<dim3(256), 256, 0, stream>>>(Wv, Wvb);
  qk_proj_kernel<<<dim3(4, 8, 2), 256, 0, stream>>>(hid, Wq, bq, Wk, bk, Qr, Kr);
  scores_softmax_kernel<<<dim3(8, 16), 256, 0, stream>>>(Qr, Kr, sinu, probs);
  vproj_kernel<<<dim3(512), 512, 0, stream>>>(hid, Wvb, bv, VT);
  ctx_kernel<<<dim3(32, 4, 16), 256, 0, stream>>>(probs, VT, out);
}